// Round 2
// baseline (308.119 us; speedup 1.0000x reference)
//
#include <hip/hip_runtime.h>

// Problem: VOCAB=10000, EMB=100, T=80, UNITS=256, BATCH=4096 — ALL FP32 I/O.
// out = sigmoid(h2_T);  h_l,t = tanh(x_l,t @ Wl + h_l,t-1 @ Ul + bl)
//
// v9 theory (from v8 counters): spills fixed (WRITE=4MB), now LDS-BW bound:
// 320 KB ds_read/CU/step (state 192 + U2 128) => ~3.9K cy floor of the
// 7.2K cy/step observed. Two structural cuts:
//  - input projection is token-indexed only => precompute P1[v][n] =
//    b1[n] + emb[v,:] @ W1 (10000x256 f16 table, f32 math). Main loop
//    GATHERS 8 f16/lane instead of 8 W1-MFMAs + emb fetch. Frees 48 VGPRs
//    (Ax + Bx frags) and 8 MFMAs/wave/step.
//  - U2 promoted from LDS (128 KB/step stream) into those freed registers:
//    U1(64) + W2(64) + U2(64) = 192 regs of weights + accs/gather/temps
//    ~= 250 <= 256/wave at waves_per_eu(2,2). LDS traffic 320 -> 208 KB/step.
// Single acc chain per tile (4 indep 8-deep MFMA chains = enough ILP),
// P1 gather prefetched one step ahead (hidden under barrier + MFMA chains).
#define BATCH 4096
#define TLEN  80
#define EMBD  100
#define UNITS 256

typedef _Float16 f16;
typedef __attribute__((ext_vector_type(8))) _Float16 h8;   // 8 f16 = 4 VGPR MFMA A/B frag
typedef __attribute__((ext_vector_type(4))) float f32x4;   // MFMA C/D frag

__device__ __forceinline__ float fast_tanh(float x) {
  x = fminf(fmaxf(x, -15.f), 15.f);
  float e = __expf(-2.f * x);
  return (1.f - e) / (1.f + e);
}
__device__ __forceinline__ float fast_sigmoid(float x) {
  x = fminf(fmaxf(x, -30.f), 30.f);
  return 1.f / (1.f + __expf(-x));
}

// ---------------- workspace layout (5.58 MB <= 6.04 MB proven available) ---
// P1 table: 10000 x 256 f16 = 5,120,000 B.  wf frags: 458,752 B.
// B-frag layout (16x16x32, r7-verified): lane holds B[k=quad*8+j][n=lane&15].
// ktg slots: W1 = 0..3 (unused by main kernel now), U1 = 4..11, W2 = 12..19,
// U2 = 20..27.  (kept identical to v8 for layout safety)
#define KT_ALL 28
#define OFF_P1 ((size_t)0)
#define P1_BYTES ((size_t)10000 * UNITS * 2)                // 5,120,000
#define OFF_WF  P1_BYTES
#define WF_BYTES ((size_t)KT_ALL * 16 * 64 * 8 * 2)         //   458,752
#define WS_NEED (OFF_WF + WF_BYTES)                          // 5,578,752 B

__device__ __forceinline__ size_t fidx(int ktg, int nt, int lane) {
  return (((size_t)ktg * 16 + nt) * 64 + lane) * 8;
}

// ---------------- precompute: weights -> swizzled fp16 B-frags (r10-verified)
__global__ __launch_bounds__(256) void k_split_w16(
    const float* __restrict__ W1, const float* __restrict__ U1,
    const float* __restrict__ W2, const float* __restrict__ U2,
    f16* __restrict__ wf)
{
  int gid = blockIdx.x * 256 + threadIdx.x;           // one per (ktg,nt,lane)
  if (gid >= KT_ALL * 16 * 64) return;
  int lane = gid & 63, nt = (gid >> 6) & 15, ktg = gid >> 10;
  const float* M; int Kact, ktl;
  if (ktg < 4)       { M = W1; Kact = EMBD;  ktl = ktg;      }
  else if (ktg < 12) { M = U1; Kact = UNITS; ktl = ktg - 4;  }
  else if (ktg < 20) { M = W2; Kact = UNITS; ktl = ktg - 12; }
  else               { M = U2; Kact = UNITS; ktl = ktg - 20; }
  int n = nt * 16 + (lane & 15);
  int kb = ktl * 32 + (lane >> 4) * 8;
  size_t base = fidx(ktg, nt, lane);
#pragma unroll
  for (int j = 0; j < 8; ++j) {
    int k = kb + j;
    wf[base + j] = (f16)((k < Kact) ? M[(size_t)k * UNITS + n] : 0.f);  // RNE
  }
}

// ---------------- precompute: P1[v][n] = b1[n] + emb[v,:] @ W1 (f32 math) --
// 625 blocks x 256 thr; block handles 16 vocab rows. emb rows staged in LDS
// (reads broadcast across all 256 threads -> conflict-free). W1 row reads are
// fully coalesced (256 consecutive floats). ~0.5 GFLOP total, a few us.
__global__ __launch_bounds__(256) void k_p1(
    const float* __restrict__ emb, const float* __restrict__ W1,
    const float* __restrict__ b1, f16* __restrict__ p1t)
{
  __shared__ float er[16][EMBD];
  const int v0 = blockIdx.x * 16;
  for (int i = threadIdx.x; i < 16 * EMBD; i += 256) {
    int vv = i / EMBD, kk = i - vv * EMBD;
    er[vv][kk] = emb[(size_t)(v0 + vv) * EMBD + kk];
  }
  __syncthreads();
  const int n = threadIdx.x;
  float acc[16];
  const float bb = b1[n];
#pragma unroll
  for (int vv = 0; vv < 16; ++vv) acc[vv] = bb;
  for (int k = 0; k < EMBD; ++k) {
    float w = W1[(size_t)k * UNITS + n];
#pragma unroll
    for (int vv = 0; vv < 16; ++vv) acc[vv] += er[vv][k] * w;
  }
#pragma unroll
  for (int vv = 0; vv < 16; ++vv)
    p1t[(size_t)(v0 + vv) * UNITS + n] = (f16)acc[vv];
}

#define MFMA16(A, B, C) __builtin_amdgcn_mfma_f32_16x16x32_f16(A, B, C, 0, 0, 0)

// store tanh result into next-step A-frag (single f16; layout r7-verified):
// elem (row=m, col=k): kt=col>>5, lane'=((col>>3)&3)*16+row, j'=col&7
__device__ __forceinline__ void store_frag1(f16* __restrict__ f, int col, int row, float v) {
  int a = (col >> 5) * 512 + (((col >> 3) & 3) * 16 + row) * 8 + (col & 7);
  f[a] = (f16)v;
}

// ---------------------------------------------------------------------------
// Main kernel v9: 512 threads = 8 waves, wave w owns n-tiles (2w, 2w+1).
// ALL recurrent weights register-resident: U1(16 frags) W2(16) U2(16) = 192
// regs, pinned. Input projection = P1 gather (12 loads/lane/step, L2-hot,
// prefetched one step ahead). LDS = 32 KB state double-buffers only.
// ---------------------------------------------------------------------------
__global__ __launch_bounds__(512, 2)
__attribute__((amdgpu_waves_per_eu(2, 2)))
void rnn_ws5(
    const int* __restrict__ idx, const f16* __restrict__ p1t,
    const f16* __restrict__ wf, const float* __restrict__ b2,
    float* __restrict__ out)
{
  __shared__ __align__(16) f16 f1[2][4096];   // [buf][kt*512 + lane*8 + j]
  __shared__ __align__(16) f16 f2[2][4096];

  const int tid  = threadIdx.x;
  const int lane = tid & 63;
  const int w    = tid >> 6;          // wave 0..7 -> n-tiles 2w, 2w+1
  const int m    = lane & 15;
  const int q    = lane >> 4;
  const int nt0  = 2 * w, nt1 = 2 * w + 1;
  const int c0   = nt0 * 16 + m;
  const int c1   = nt1 * 16 + m;
  const int b0   = blockIdx.x * 16;

  const float b2a = b2[c0], b2b = b2[c1];
  // tokens for the 4 batch rows this lane's accumulator covers (rows q*4+r)
  const int* tokq = idx + (size_t)(b0 + q * 4) * TLEN;

  // -------- persistent weight fragments: U1, W2, U2 (2 n-tiles each) -------
  h8 Bu1a[8], Bu1b[8], Bw2a[8], Bw2b[8], Bu2a[8], Bu2b[8];
#pragma unroll
  for (int kt = 0; kt < 8; ++kt) {
    Bu1a[kt] = *(const h8*)(wf + fidx(4 + kt, nt0, lane));
    Bu1b[kt] = *(const h8*)(wf + fidx(4 + kt, nt1, lane));
    Bw2a[kt] = *(const h8*)(wf + fidx(12 + kt, nt0, lane));
    Bw2b[kt] = *(const h8*)(wf + fidx(12 + kt, nt1, lane));
    Bu2a[kt] = *(const h8*)(wf + fidx(20 + kt, nt0, lane));
    Bu2b[kt] = *(const h8*)(wf + fidx(20 + kt, nt1, lane));
  }
  // pin: origin becomes the asm -> no remat; values must stay resident
#pragma unroll
  for (int kt = 0; kt < 8; ++kt) {
    asm volatile("" : "+v"(Bu1a[kt])); asm volatile("" : "+v"(Bu1b[kt]));
    asm volatile("" : "+v"(Bw2a[kt])); asm volatile("" : "+v"(Bw2b[kt]));
    asm volatile("" : "+v"(Bu2a[kt])); asm volatile("" : "+v"(Bu2b[kt]));
  }

  // t=0 input-projection gather (f16 table, cvt to f32)
  float pa[4], pb[4];
#pragma unroll
  for (int r = 0; r < 4; ++r) {
    int tk = tokq[(size_t)r * TLEN + 0];
    const f16* pr = p1t + (size_t)tk * UNITS;
    pa[r] = (float)pr[c0];
    pb[r] = (float)pr[c1];
  }

  for (int i = tid; i < 4096; i += 512) {
    f1[0][i] = (f16)0.f;
    f2[0][i] = (f16)0.f;
  }
  __syncthreads();

  for (int t = 0; t < TLEN; ++t) {
    const int p = t & 1, qb = p ^ 1;

    // ---- layer 1: a1 = P1[tok] + h1_old @ U1 (single chain per tile) -----
    f32x4 x0 = (f32x4){0.f, 0.f, 0.f, 0.f};
    f32x4 x1 = (f32x4){0.f, 0.f, 0.f, 0.f};
#pragma unroll
    for (int kt = 0; kt < 8; ++kt) {
      h8 ah = *(const h8*)&f1[p][kt * 512 + lane * 8];
      x0 = MFMA16(ah, Bu1a[kt], x0);
      x1 = MFMA16(ah, Bu1b[kt], x1);
    }

    // ---- layer 2 pre-barrier half: h2_old @ U2 (reg-resident B) -----------
    f32x4 y0 = (f32x4){0.f, 0.f, 0.f, 0.f};
    f32x4 y1 = (f32x4){0.f, 0.f, 0.f, 0.f};
#pragma unroll
    for (int kt = 0; kt < 8; ++kt) {
      h8 ah = *(const h8*)&f2[p][kt * 512 + lane * 8];
      y0 = MFMA16(ah, Bu2a[kt], y0);
      y1 = MFMA16(ah, Bu2b[kt], y1);
    }

    // ---- layer-1 epilogue: tanh(P1 + U1h) -> next A-frag ------------------
#pragma unroll
    for (int r = 0; r < 4; ++r) {
      store_frag1(f1[qb], c0, q * 4 + r, fast_tanh(x0[r] + pa[r]));
      store_frag1(f1[qb], c1, q * 4 + r, fast_tanh(x1[r] + pb[r]));
    }
    // prefetch next step's P1 gather (hidden under barrier + layer-2 chain)
    if (t + 1 < TLEN) {
#pragma unroll
      for (int r = 0; r < 4; ++r) {
        int tk = tokq[(size_t)r * TLEN + (t + 1)];
        const f16* pr = p1t + (size_t)tk * UNITS;
        pa[r] = (float)pr[c0];
        pb[r] = (float)pr[c1];
      }
    }
    __syncthreads();                           // barrier 1: f1[qb] visible

    // ---- layer 2 post-barrier half: h1_new @ W2 ---------------------------
#pragma unroll
    for (int kt = 0; kt < 8; ++kt) {
      h8 ah = *(const h8*)&f1[qb][kt * 512 + lane * 8];
      y0 = MFMA16(ah, Bw2a[kt], y0);
      y1 = MFMA16(ah, Bw2b[kt], y1);
    }
#pragma unroll
    for (int r = 0; r < 4; ++r) {
      int row = q * 4 + r;
      float t0 = fast_tanh(y0[r] + b2a);
      float t1 = fast_tanh(y1[r] + b2b);
      store_frag1(f2[qb], c0, row, t0);
      store_frag1(f2[qb], c1, row, t1);
      if (t == TLEN - 1) {
        out[(size_t)(b0 + row) * UNITS + c0] = fast_sigmoid(t0);
        out[(size_t)(b0 + row) * UNITS + c1] = fast_sigmoid(t1);
      }
    }
    __syncthreads();                           // barrier 2: f2[qb] visible
  }
}

// ---------------------------------------------------------------------------
extern "C" void kernel_launch(void* const* d_in, const int* in_sizes, int n_in,
                              void* d_out, int out_size, void* d_ws, size_t ws_size,
                              hipStream_t stream)
{
  const int*   idx = (const int*)d_in[0];
  const float* emb = (const float*)d_in[1];
  const float* W1  = (const float*)d_in[2];
  const float* U1  = (const float*)d_in[3];
  const float* b1  = (const float*)d_in[4];
  const float* W2  = (const float*)d_in[5];
  const float* U2  = (const float*)d_in[6];
  const float* b2  = (const float*)d_in[7];
  // d_in[8] (Wd), d_in[9] (bd) dead in the reference output.
  float* out = (float*)d_out;

  f16* p1t = (f16*)((char*)d_ws + OFF_P1);
  f16* wf  = (f16*)((char*)d_ws + OFF_WF);
  k_p1<<<10000 / 16, 256, 0, stream>>>(emb, W1, b1, p1t);
  k_split_w16<<<(KT_ALL * 16 * 64 + 255) / 256, 256, 0, stream>>>(W1, U1, W2, U2, wf);
  rnn_ws5<<<BATCH / 16, 512, 0, stream>>>(idx, p1t, wf, b2, out);
}